// Round 3
// baseline (346.436 us; speedup 1.0000x reference)
//
#include <hip/hip_runtime.h>

typedef unsigned short u16;
typedef unsigned int   u32;
typedef unsigned long long u64;
typedef __attribute__((ext_vector_type(8))) short bf16x8;
typedef __attribute__((ext_vector_type(4))) float f32x4;

#define NOBS 128
#define NN   1280
#define NH   256
#define NO   80
#define TT   5
#define RR   16          // batch rows per block
#define AP   72          // ldsA pitch (bf16): 64 + 8 pad
#define BP   72          // ldsB pitch
#define NROW (TT*RR)     // 80 GEMM rows (t-major tiles of 16)

// ws layout (u16 units), 3-way bf16 split (hi | mid | lo grouped per matrix):
//   W1s [3][20][256][64] @0          (983040)
//   W2s [3][4][256][64]  @983040     (196608)
//   Wos [3][4][128][64]  @1179648    (98304, rows padded to 128)
#define W1TOT   983040
#define W2S_OFF 983040
#define WOS_OFF 1179648
#define WS_TOTAL 1277952

__device__ __forceinline__ float bf2f(u16 u) {
  union { u32 i; float f; } x; x.i = ((u32)u) << 16; return x.f;
}
__device__ __forceinline__ u16 f2bf(float f) {
  union { float f; u32 i; } x; x.f = f;
  u32 i = x.i + 0x7FFFu + ((x.i >> 16) & 1u);   // RNE
  return (u16)(i >> 16);
}

// 3-way bf16 split: w ~= hi + mid + lo, residual <= 2^-27 |w|.
// Products with exact 0/1 spikes are exact -> f32-level GEMM accuracy.
__device__ __forceinline__ u16 split3(float w, int sel) {
  u16 hi = f2bf(w);
  if (sel == 0) return hi;
  float r1 = __fsub_rn(w, bf2f(hi));        // exact (Sterbenz)
  u16 mid = f2bf(r1);
  if (sel == 1) return mid;
  float r2 = __fsub_rn(r1, bf2f(mid));      // exact
  return f2bf(r2);
}

__global__ __launch_bounds__(256) void prep_kernel(
    const float* __restrict__ W1, const float* __restrict__ W2,
    const float* __restrict__ Wo, u16* __restrict__ ws)
{
  int i = blockIdx.x * 256 + threadIdx.x;
  if (i < W1TOT) {                          // W1 [256][1280]
    int sel = i / 327680, rem = i - sel * 327680;
    int kc = rem >> 14, r = rem & 16383, j = r >> 6, kk = r & 63;
    float w = W1[j * 1280 + kc * 64 + kk];
    ws[i] = split3(w, sel);
  } else if (i < WOS_OFF) {                 // W2 [256][256]
    int i2 = i - W2S_OFF;
    int sel = i2 >> 16, rem = i2 & 65535;
    int kc = rem >> 14, j = (rem >> 6) & 255, kk = rem & 63;
    float w = W2[j * 256 + kc * 64 + kk];
    ws[i] = split3(w, sel);
  } else if (i < WS_TOTAL) {                // Wo [80][256] padded to 128 rows
    int i3 = i - WOS_OFF;
    int sel = i3 >> 15, rem = i3 & 32767;
    int kc = rem >> 13, j = (rem >> 6) & 127, kk = rem & 63;
    float w = (j < NO) ? Wo[j * 256 + kc * 64 + kk] : 0.f;
    ws[i] = split3(w, sel);
  }
}

// GEMM: A = spike bits [NROW x K] expanded to bf16, B = ws blocks [kc2][n][64].
// kreal = kc2 % kmod maps split-group chunks back to their K-bit range.
template <int NCT>
__device__ __forceinline__ void gemm_bits(
    u16 (*ldsA)[AP], u16 (*ldsB)[BP],
    const u16* __restrict__ Bglob, int nkc2, int kmod, int nrowB,
    const u16* bits, int bpitch,    // u16 words per (t,row)
    int tid, int lane, int ct0,
    f32x4 acc[TT][4])
{
  const int m16 = lane & 15, q = lane >> 4;
  for (int kc2 = 0; kc2 < nkc2; ++kc2) {
    const int kreal = kc2 % kmod;
    // stage B chunk: [nrowB][64] bf16
    const u16* src = Bglob + kc2 * nrowB * 64;
    for (int idx = tid; idx < nrowB * 8; idx += 256) {
      int row = idx >> 3, v = idx & 7;
      uint4 d = *(const uint4*)(src + (row << 6) + (v << 3));
      *(uint4*)(&ldsB[row][v << 3]) = d;
    }
    // stage A chunk: expand bits -> bf16 (2 per u32 store)
    for (int idx = tid; idx < NROW * 32; idx += 256) {
      int row = idx >> 5, pr = idx & 31;
      int t = row >> 4, r = row & 15;
      int kg = (kreal << 6) + (pr << 1);
      u16 w = bits[(t * RR + r) * bpitch + (kg >> 4)];
      int bp = kg & 15;
      u32 val = ((w >> bp) & 1) ? 0x3F80u : 0u;
      if ((w >> (bp + 1)) & 1) val |= 0x3F800000u;
      *(u32*)(&ldsA[row][pr << 1]) = val;
    }
    __syncthreads();
    #pragma unroll
    for (int ks = 0; ks < 2; ++ks) {
      bf16x8 afr[TT];
      #pragma unroll
      for (int t = 0; t < TT; ++t)
        afr[t] = *(const bf16x8*)(&ldsA[t * 16 + m16][ks * 32 + q * 8]);
      #pragma unroll
      for (int i = 0; i < NCT; ++i) {
        const bf16x8 bfr = *(const bf16x8*)(&ldsB[(ct0 + i) * 16 + m16][ks * 32 + q * 8]);
        #pragma unroll
        for (int t = 0; t < TT; ++t)
          acc[t][i] = __builtin_amdgcn_mfma_f32_16x16x32_bf16(afr[t], bfr, acc[t][i], 0, 0, 0);
      }
    }
    __syncthreads();
  }
}

// LIF recurrence over t on accumulated u(t); emit spike bits via ballot
__device__ __forceinline__ void recur_spikes(
    f32x4 acc[TT][4], const float* __restrict__ bias,
    int lane, int ct0, u16* sbits /* [TT][RR][16] words */)
{
  const int q = lane >> 4, m16 = lane & 15;
  #pragma unroll
  for (int i = 0; i < 4; ++i) {
    int j = (ct0 + i) * 16 + m16;
    float bj = bias[j];
    #pragma unroll
    for (int rg = 0; rg < 4; ++rg) {
      float c = 0.f, v = 0.f, sprev = 0.f;
      #pragma unroll
      for (int t = 0; t < TT; ++t) {
        float u = acc[t][i][rg];
        c = __fadd_rn(__fadd_rn(__fmul_rn(c, 0.5f), u), bj);       // (c*0.5 + u) + b
        float vd = __fmul_rn(v, 0.75f);
        v = __fadd_rn((sprev > 0.5f) ? 0.f : vd, c);               // v*0.75*(1-s) + c
        bool sp = v > 0.5f;
        u64 mask = __ballot(sp);
        if (m16 == 0) {
          int row = q * 4 + rg;
          sbits[(t * RR + row) * 16 + (ct0 + i)] = (u16)(mask >> (q * 16));
        }
        sprev = sp ? 1.f : 0.f;
      }
    }
  }
}

__global__ __launch_bounds__(256, 2) void snn_main(
    const float* __restrict__ obs, const float* __restrict__ enc_mean, const float* __restrict__ enc_std,
    const float* __restrict__ b1, const float* __restrict__ b2, const float* __restrict__ bo,
    const float* __restrict__ dec_w, const float* __restrict__ dec_b, const float* __restrict__ log_std,
    const u16* __restrict__ wsW, float* __restrict__ out, int Btot)
{
  __shared__ __align__(16) char smem[61184];
  u16 (*ldsA)[AP] = (u16(*)[AP])smem;                         // 80*72*2  = 11520
  u16 (*ldsB)[BP] = (u16(*)[BP])(smem + NROW * AP * 2);       // 256*72*2 = 36864
  u16* encb = (u16*)(smem + NROW * AP * 2 + NH * BP * 2);     // [5][16][80] u16 = 12800 B
  u16* s1b  = encb;                                           // [5][16][16] (alias: encb dead after GEMM1)
  u16* s2b  = encb + TT * RR * 16;                            // [5][16][16]
  float* soacc = (float*)(encb + 2 * TT * RR * 16);           // [16][80] f32 (tail of enc region)

  const int tid  = threadIdx.x;
  const int lane = tid & 63;
  const int wv   = tid >> 6;
  const int r0   = blockIdx.x * RR;

  // ---------- population encoder -> spike bits for all T ----------
  for (int slot = tid; slot < RR * 20; slot += 256) {
    int r = slot / 20, c = slot - (slot / 20) * 20;
    u64 bits[TT] = {0, 0, 0, 0, 0};
    const float* obsrow = obs + (r0 + r) * NOBS;
    for (int e = 0; e < 64; ++e) {
      int k = c * 64 + e;
      int f = k / 10;
      float x  = obsrow[f];
      float m  = enc_mean[k];           // flat [f*10+p] == k
      float sd = enc_std[k];
      float d  = __fsub_rn(x, m);
      float arg = __fdiv_rn(__fmul_rn(-0.5f, __fmul_rn(d, d)), __fmul_rn(sd, sd));
      float a = (float)exp((double)arg);   // correctly-rounded f32 exp of f32 arg
      float v = 0.f;
      #pragma unroll
      for (int t = 0; t < TT; ++t) {
        v = __fadd_rn(v, a);
        if (v > 0.999f) { bits[t] |= (1ull << e); v = __fsub_rn(v, 0.999f); }
      }
    }
    #pragma unroll
    for (int t = 0; t < TT; ++t) {
      u16* dst = encb + (t * RR + r) * 80 + c * 4;
      u64 bt = bits[t];
      dst[0] = (u16)bt; dst[1] = (u16)(bt >> 16);
      dst[2] = (u16)(bt >> 32); dst[3] = (u16)(bt >> 48);
    }
  }
  __syncthreads();

  f32x4 accA[TT][4], accB[TT][4];
  const f32x4 zero4 = {0.f, 0.f, 0.f, 0.f};
#define ZERO_ACC(A) { _Pragma("unroll") for (int t = 0; t < TT; ++t) \
                      _Pragma("unroll") for (int i = 0; i < 4; ++i) A[t][i] = zero4; }
#define COMBINE()   { _Pragma("unroll") for (int t = 0; t < TT; ++t) \
                      _Pragma("unroll") for (int i = 0; i < 4; ++i) accA[t][i] += accB[t][i]; }

  // ---------- layer 1: [80 x 1280] @ [1280 x 256] ----------
  ZERO_ACC(accA); ZERO_ACC(accB);
  gemm_bits<4>(ldsA, ldsB, wsW,               20, 20, 256, encb, 80, tid, lane, wv * 4, accA);
  gemm_bits<4>(ldsA, ldsB, wsW + 20 * 16384,  40, 20, 256, encb, 80, tid, lane, wv * 4, accB);
  COMBINE();
  recur_spikes(accA, b1, lane, wv * 4, s1b);
  __syncthreads();

  // ---------- layer 2: [80 x 256] @ [256 x 256] ----------
  ZERO_ACC(accA); ZERO_ACC(accB);
  gemm_bits<4>(ldsA, ldsB, wsW + W2S_OFF,             4, 4, 256, s1b, 16, tid, lane, wv * 4, accA);
  gemm_bits<4>(ldsA, ldsB, wsW + W2S_OFF + 4 * 16384, 8, 4, 256, s1b, 16, tid, lane, wv * 4, accB);
  COMBINE();
  recur_spikes(accA, b2, lane, wv * 4, s2b);
  __syncthreads();

  // ---------- layer 3: [80 x 256] @ [256 x 80(pad128)] ----------
  ZERO_ACC(accA); ZERO_ACC(accB);
  gemm_bits<2>(ldsA, ldsB, wsW + WOS_OFF,            4, 4, 128, s2b, 16, tid, lane, wv * 2, accA);
  gemm_bits<2>(ldsA, ldsB, wsW + WOS_OFF + 4 * 8192, 8, 4, 128, s2b, 16, tid, lane, wv * 2, accB);
  COMBINE();
  {
    const int q = lane >> 4, m16 = lane & 15;
    #pragma unroll
    for (int i = 0; i < 2; ++i) {
      int j = (wv * 2 + i) * 16 + m16;
      bool valid = j < NO;
      float bj = valid ? bo[j] : 0.f;
      #pragma unroll
      for (int rg = 0; rg < 4; ++rg) {
        float c = 0.f, v = 0.f, sprev = 0.f;
        int cnt = 0;
        #pragma unroll
        for (int t = 0; t < TT; ++t) {
          float u = accA[t][i][rg];
          c = __fadd_rn(__fadd_rn(__fmul_rn(c, 0.5f), u), bj);
          float vd = __fmul_rn(v, 0.75f);
          v = __fadd_rn((sprev > 0.5f) ? 0.f : vd, c);
          bool sp = v > 0.5f;
          cnt += sp ? 1 : 0;
          sprev = sp ? 1.f : 0.f;
        }
        if (valid) soacc[(q * 4 + rg) * NO + j] = __fdiv_rn((float)cnt, 5.0f);
      }
    }
  }
  __syncthreads();

  // ---------- decoder: grouped dot + ELU ----------
  if (tid < RR * 8) {
    int r = tid >> 3, a = tid & 7;
    float s = 0.f;
    const float* so = soacc + r * NO + a * 10;
    #pragma unroll
    for (int p = 0; p < 10; ++p)
      s = __fadd_rn(s, __fmul_rn(so[p], dec_w[a * 10 + p]));
    s = __fadd_rn(s, dec_b[a]);
    float mu = (s > 0.f) ? s : expm1f(s);
    out[(r0 + r) * 8 + a] = mu;
  }
  if (blockIdx.x == 0 && tid < 8) {
    out[Btot * 8 + tid] = expf(log_std[tid]);
  }
}

extern "C" void kernel_launch(void* const* d_in, const int* in_sizes, int n_in,
                              void* d_out, int out_size, void* d_ws, size_t ws_size,
                              hipStream_t stream) {
  const float* obs      = (const float*)d_in[0];
  const float* enc_mean = (const float*)d_in[1];
  const float* enc_std  = (const float*)d_in[2];
  const float* W1       = (const float*)d_in[3];
  const float* b1       = (const float*)d_in[4];
  const float* W2       = (const float*)d_in[5];
  const float* b2       = (const float*)d_in[6];
  const float* Wo       = (const float*)d_in[7];
  const float* bo       = (const float*)d_in[8];
  const float* dec_w    = (const float*)d_in[9];
  const float* dec_b    = (const float*)d_in[10];
  const float* log_std  = (const float*)d_in[11];
  u16*   ws  = (u16*)d_ws;
  float* out = (float*)d_out;
  int B = in_sizes[0] / NOBS;   // 8192

  hipLaunchKernelGGL(prep_kernel, dim3(WS_TOTAL / 256), dim3(256), 0, stream,
                     W1, W2, Wo, ws);
  hipLaunchKernelGGL(snn_main, dim3(B / RR), dim3(256), 0, stream,
                     obs, enc_mean, enc_std, b1, b2, bo, dec_w, dec_b, log_std, ws, out, B);
}

// Round 4
// 326.195 us; speedup vs baseline: 1.0621x; 1.0621x over previous
//
#include <hip/hip_runtime.h>

typedef unsigned short u16;
typedef unsigned int   u32;
typedef unsigned long long u64;
typedef __attribute__((ext_vector_type(8))) short bf16x8;
typedef __attribute__((ext_vector_type(4))) float f32x4;

#define NOBS 128
#define NN   1280
#define NH   256
#define NO   80
#define TT   5
#define RR   16          // batch rows per block
#define AP   72          // ldsA pitch (bf16): 64 + 8 pad (2-way bank alias = free)
#define NROW (TT*RR)     // 80 GEMM rows (t-major tiles of 16)

// ws layout (u16 units), 3-way bf16 split (hi | mid | lo grouped per matrix):
//   W1s [3][20][256][64] @0          (983040)
//   W2s [3][4][256][64]  @983040     (196608)
//   Wos [3][4][128][64]  @1179648    (98304, rows padded to 128)
#define W1TOT   983040
#define W2S_OFF 983040
#define WOS_OFF 1179648
#define WS_TOTAL 1277952

__device__ __forceinline__ float bf2f(u16 u) {
  union { u32 i; float f; } x; x.i = ((u32)u) << 16; return x.f;
}
__device__ __forceinline__ u16 f2bf(float f) {
  union { float f; u32 i; } x; x.f = f;
  u32 i = x.i + 0x7FFFu + ((x.i >> 16) & 1u);   // RNE
  return (u16)(i >> 16);
}

// 3-way bf16 split: w ~= hi + mid + lo, residual <= 2^-27 |w|.
// Products with exact 0/1 spikes are exact -> f32-level GEMM accuracy.
__device__ __forceinline__ u16 split3(float w, int sel) {
  u16 hi = f2bf(w);
  if (sel == 0) return hi;
  float r1 = __fsub_rn(w, bf2f(hi));        // exact
  u16 mid = f2bf(r1);
  if (sel == 1) return mid;
  float r2 = __fsub_rn(r1, bf2f(mid));      // exact
  return f2bf(r2);
}

__global__ __launch_bounds__(256) void prep_kernel(
    const float* __restrict__ W1, const float* __restrict__ W2,
    const float* __restrict__ Wo, u16* __restrict__ ws)
{
  int i = blockIdx.x * 256 + threadIdx.x;
  if (i < W1TOT) {                          // W1 [256][1280]
    int sel = i / 327680, rem = i - sel * 327680;
    int kc = rem >> 14, r = rem & 16383, j = r >> 6, kk = r & 63;
    float w = W1[j * 1280 + kc * 64 + kk];
    ws[i] = split3(w, sel);
  } else if (i < WOS_OFF) {                 // W2 [256][256]
    int i2 = i - W2S_OFF;
    int sel = i2 >> 16, rem = i2 & 65535;
    int kc = rem >> 14, j = (rem >> 6) & 255, kk = rem & 63;
    float w = W2[j * 256 + kc * 64 + kk];
    ws[i] = split3(w, sel);
  } else if (i < WS_TOTAL) {                // Wo [80][256] padded to 128 rows
    int i3 = i - WOS_OFF;
    int sel = i3 >> 15, rem = i3 & 32767;
    int kc = rem >> 13, j = (rem >> 6) & 127, kk = rem & 63;
    float w = (j < NO) ? Wo[j * 256 + kc * 64 + kk] : 0.f;
    ws[i] = split3(w, sel);
  }
}

// cooperative expansion of one 64-bit K-chunk of spike bits -> bf16 LDS tile
__device__ __forceinline__ void expandA(
    u16 (*buf)[AP], const u16* bits, int bpitch, int kreal, int tid)
{
  #pragma unroll
  for (int it = 0; it < (NROW * 32) / 256; ++it) {   // 10 iters
    int idx = tid + it * 256;
    int row = idx >> 5, pr = idx & 31;
    int t = row >> 4, r = row & 15;
    int kg = (kreal << 6) + (pr << 1);
    u16 w = bits[(t * RR + r) * bpitch + (kg >> 4)];
    int bp = kg & 15;
    u32 val = ((w >> bp) & 1) ? 0x3F80u : 0u;
    if ((w >> (bp + 1)) & 1) val |= 0x3F800000u;
    *(u32*)(&buf[row][pr << 1]) = val;
  }
}

// Merged-split GEMM: per K-chunk, A expanded once (double-buffered LDS),
// B fragments loaded per-wave directly from global (L2-resident ws).
// sel=0 (hi) -> accA ; sel=1,2 (mid,lo) -> accB.
template <int NCT>
__device__ __forceinline__ void gemm_merged(
    u16 (*ldsA)[NROW][AP],
    const u16* __restrict__ wsbase, int selstride, int nkreal, int nrowB,
    const u16* bits, int bpitch,
    int tid, int lane, int ct0,
    f32x4 accA[TT][4], f32x4 accB[TT][4])
{
  const int m16 = lane & 15, q = lane >> 4;
  int rowoff[NCT];
  #pragma unroll
  for (int i = 0; i < NCT; ++i)
    rowoff[i] = ((ct0 + i) * 16 + m16) * 64 + q * 8;   // u16 units within chunk

  expandA(ldsA[0], bits, bpitch, 0, tid);
  __syncthreads();

  for (int kr = 0; kr < nkreal; ++kr) {
    const int par = kr & 1;
    const u16* cbase = wsbase + kr * (nrowB * 64);
    #pragma unroll
    for (int ks = 0; ks < 2; ++ks) {
      bf16x8 afr[TT];
      #pragma unroll
      for (int t = 0; t < TT; ++t)
        afr[t] = *(const bf16x8*)(&ldsA[par][t * 16 + m16][ks * 32 + q * 8]);
      #pragma unroll
      for (int sel = 0; sel < 3; ++sel) {
        const u16* sb = cbase + sel * selstride + ks * 32;
        f32x4 (*acc)[4] = sel ? accB : accA;
        #pragma unroll
        for (int i = 0; i < NCT; ++i) {
          const bf16x8 bfr = *(const bf16x8*)(sb + rowoff[i]);
          #pragma unroll
          for (int t = 0; t < TT; ++t)
            acc[t][i] = __builtin_amdgcn_mfma_f32_16x16x32_bf16(afr[t], bfr, acc[t][i], 0, 0, 0);
        }
      }
    }
    if (kr + 1 < nkreal) expandA(ldsA[par ^ 1], bits, bpitch, kr + 1, tid);
    __syncthreads();
  }
}

// LIF recurrence over t on accumulated u(t); emit spike bits via ballot
__device__ __forceinline__ void recur_spikes(
    f32x4 acc[TT][4], const float* __restrict__ bias,
    int lane, int ct0, u16* sbits /* [TT][RR][16] words */)
{
  const int q = lane >> 4, m16 = lane & 15;
  #pragma unroll
  for (int i = 0; i < 4; ++i) {
    int j = (ct0 + i) * 16 + m16;
    float bj = bias[j];
    #pragma unroll
    for (int rg = 0; rg < 4; ++rg) {
      float c = 0.f, v = 0.f, sprev = 0.f;
      #pragma unroll
      for (int t = 0; t < TT; ++t) {
        float u = acc[t][i][rg];
        c = __fadd_rn(__fadd_rn(__fmul_rn(c, 0.5f), u), bj);       // (c*0.5 + u) + b
        float vd = __fmul_rn(v, 0.75f);
        v = __fadd_rn((sprev > 0.5f) ? 0.f : vd, c);               // v*0.75*(1-s) + c
        bool sp = v > 0.5f;
        u64 mask = __ballot(sp);
        if (m16 == 0) {
          int row = q * 4 + rg;
          sbits[(t * RR + row) * 16 + (ct0 + i)] = (u16)(mask >> (q * 16));
        }
        sprev = sp ? 1.f : 0.f;
      }
    }
  }
}

__global__ __launch_bounds__(256, 2) void snn_main(
    const float* __restrict__ obs, const float* __restrict__ enc_mean, const float* __restrict__ enc_std,
    const float* __restrict__ b1, const float* __restrict__ b2, const float* __restrict__ bo,
    const float* __restrict__ dec_w, const float* __restrict__ dec_b, const float* __restrict__ log_std,
    const u16* __restrict__ wsW, float* __restrict__ out, int Btot)
{
  __shared__ __align__(16) char smem[2 * NROW * AP * 2 + 12800];
  u16 (*ldsA)[NROW][AP] = (u16(*)[NROW][AP])smem;             // 2*80*72*2 = 23040
  u16* encb = (u16*)(smem + 2 * NROW * AP * 2);               // [5][16][80] u16 = 12800 B
  u16* s1b  = encb;                                           // [5][16][16] (alias: encb dead after layer1)
  u16* s2b  = encb + TT * RR * 16;                            // [5][16][16]
  float* soacc = (float*)(encb + 2 * TT * RR * 16);           // [16][80] f32 (tail of enc region)

  const int tid  = threadIdx.x;
  const int lane = tid & 63;
  const int wv   = tid >> 6;
  const int r0   = blockIdx.x * RR;

  // ---------- population encoder -> spike bits for all T ----------
  for (int slot = tid; slot < RR * 20; slot += 256) {
    int r = slot / 20, c = slot - (slot / 20) * 20;
    u64 bits[TT] = {0, 0, 0, 0, 0};
    const float* obsrow = obs + (r0 + r) * NOBS;
    for (int e = 0; e < 64; ++e) {
      int k = c * 64 + e;
      int f = k / 10;
      float x  = obsrow[f];
      float m  = enc_mean[k];
      float sd = enc_std[k];
      float d  = __fsub_rn(x, m);
      float arg = __fdiv_rn(__fmul_rn(-0.5f, __fmul_rn(d, d)), __fmul_rn(sd, sd));
      float a = (float)exp((double)arg);   // correctly-rounded f32 exp of f32 arg
      float v = 0.f;
      #pragma unroll
      for (int t = 0; t < TT; ++t) {
        v = __fadd_rn(v, a);
        if (v > 0.999f) { bits[t] |= (1ull << e); v = __fsub_rn(v, 0.999f); }
      }
    }
    #pragma unroll
    for (int t = 0; t < TT; ++t) {
      u16* dst = encb + (t * RR + r) * 80 + c * 4;
      u64 bt = bits[t];
      dst[0] = (u16)bt; dst[1] = (u16)(bt >> 16);
      dst[2] = (u16)(bt >> 32); dst[3] = (u16)(bt >> 48);
    }
  }
  __syncthreads();

  f32x4 accA[TT][4], accB[TT][4];
  const f32x4 zero4 = {0.f, 0.f, 0.f, 0.f};
#define ZERO_ACC() { _Pragma("unroll") for (int t = 0; t < TT; ++t) \
                     _Pragma("unroll") for (int i = 0; i < 4; ++i) { accA[t][i] = zero4; accB[t][i] = zero4; } }
#define COMBINE()  { _Pragma("unroll") for (int t = 0; t < TT; ++t) \
                     _Pragma("unroll") for (int i = 0; i < 4; ++i) accA[t][i] += accB[t][i]; }

  // ---------- layer 1: [80 x 1280] @ [1280 x 256] (3-way split fused) ----------
  ZERO_ACC();
  gemm_merged<4>(ldsA, wsW, 327680, 20, 256, encb, 80, tid, lane, wv * 4, accA, accB);
  COMBINE();
  recur_spikes(accA, b1, lane, wv * 4, s1b);
  __syncthreads();

  // ---------- layer 2: [80 x 256] @ [256 x 256] ----------
  ZERO_ACC();
  gemm_merged<4>(ldsA, wsW + W2S_OFF, 65536, 4, 256, s1b, 16, tid, lane, wv * 4, accA, accB);
  COMBINE();
  recur_spikes(accA, b2, lane, wv * 4, s2b);
  __syncthreads();

  // ---------- layer 3: [80 x 256] @ [256 x 80(pad128)] ----------
  ZERO_ACC();
  gemm_merged<2>(ldsA, wsW + WOS_OFF, 32768, 4, 128, s2b, 16, tid, lane, wv * 2, accA, accB);
  COMBINE();
  {
    const int q = lane >> 4, m16 = lane & 15;
    #pragma unroll
    for (int i = 0; i < 2; ++i) {
      int j = (wv * 2 + i) * 16 + m16;
      bool valid = j < NO;
      float bj = valid ? bo[j] : 0.f;
      #pragma unroll
      for (int rg = 0; rg < 4; ++rg) {
        float c = 0.f, v = 0.f, sprev = 0.f;
        int cnt = 0;
        #pragma unroll
        for (int t = 0; t < TT; ++t) {
          float u = accA[t][i][rg];
          c = __fadd_rn(__fadd_rn(__fmul_rn(c, 0.5f), u), bj);
          float vd = __fmul_rn(v, 0.75f);
          v = __fadd_rn((sprev > 0.5f) ? 0.f : vd, c);
          bool sp = v > 0.5f;
          cnt += sp ? 1 : 0;
          sprev = sp ? 1.f : 0.f;
        }
        if (valid) soacc[(q * 4 + rg) * NO + j] = __fdiv_rn((float)cnt, 5.0f);
      }
    }
  }
  __syncthreads();

  // ---------- decoder: grouped dot + ELU ----------
  if (tid < RR * 8) {
    int r = tid >> 3, a = tid & 7;
    float s = 0.f;
    const float* so = soacc + r * NO + a * 10;
    #pragma unroll
    for (int p = 0; p < 10; ++p)
      s = __fadd_rn(s, __fmul_rn(so[p], dec_w[a * 10 + p]));
    s = __fadd_rn(s, dec_b[a]);
    float mu = (s > 0.f) ? s : expm1f(s);
    out[(r0 + r) * 8 + a] = mu;
  }
  if (blockIdx.x == 0 && tid < 8) {
    out[Btot * 8 + tid] = expf(log_std[tid]);
  }
}

extern "C" void kernel_launch(void* const* d_in, const int* in_sizes, int n_in,
                              void* d_out, int out_size, void* d_ws, size_t ws_size,
                              hipStream_t stream) {
  const float* obs      = (const float*)d_in[0];
  const float* enc_mean = (const float*)d_in[1];
  const float* enc_std  = (const float*)d_in[2];
  const float* W1       = (const float*)d_in[3];
  const float* b1       = (const float*)d_in[4];
  const float* W2       = (const float*)d_in[5];
  const float* b2       = (const float*)d_in[6];
  const float* Wo       = (const float*)d_in[7];
  const float* bo       = (const float*)d_in[8];
  const float* dec_w    = (const float*)d_in[9];
  const float* dec_b    = (const float*)d_in[10];
  const float* log_std  = (const float*)d_in[11];
  u16*   ws  = (u16*)d_ws;
  float* out = (float*)d_out;
  int B = in_sizes[0] / NOBS;   // 8192

  hipLaunchKernelGGL(prep_kernel, dim3(WS_TOTAL / 256), dim3(256), 0, stream,
                     W1, W2, Wo, ws);
  hipLaunchKernelGGL(snn_main, dim3(B / RR), dim3(256), 0, stream,
                     obs, enc_mean, enc_std, b1, b2, bo, dec_w, dec_b, log_std, ws, out, B);
}

// Round 5
// 283.956 us; speedup vs baseline: 1.2200x; 1.1487x over previous
//
#include <hip/hip_runtime.h>

typedef unsigned short u16;
typedef unsigned int   u32;
typedef unsigned long long u64;
typedef __attribute__((ext_vector_type(8))) short bf16x8;
typedef __attribute__((ext_vector_type(4))) float f32x4;

#define NOBS 128
#define NN   1280
#define NH   256
#define NO   80
#define TT   5
#define RR   16          // batch rows per block
#define AP   72          // ldsA pitch (bf16): 64 + 8 pad (2-way bank alias = free)
#define NROW (TT*RR)     // 80 GEMM rows (t-major tiles of 16)
#define NTHR 1024        // 16 waves/block, 1 col-tile per wave -> 40 acc regs/thread

// ws layout (u16 units), 3-way bf16 split (hi | mid | lo grouped per matrix):
//   W1s [3][20][256][64] @0          (983040)
//   W2s [3][4][256][64]  @983040     (196608)
//   Wos [3][4][128][64]  @1179648    (98304, rows padded to 128)
#define W1TOT   983040
#define W2S_OFF 983040
#define WOS_OFF 1179648
#define WS_TOTAL 1277952

__device__ __forceinline__ float bf2f(u16 u) {
  union { u32 i; float f; } x; x.i = ((u32)u) << 16; return x.f;
}
__device__ __forceinline__ u16 f2bf(float f) {
  union { float f; u32 i; } x; x.f = f;
  u32 i = x.i + 0x7FFFu + ((x.i >> 16) & 1u);   // RNE
  return (u16)(i >> 16);
}

// 3-way bf16 split: w ~= hi + mid + lo, residual <= 2^-27 |w|.
__device__ __forceinline__ u16 split3(float w, int sel) {
  u16 hi = f2bf(w);
  if (sel == 0) return hi;
  float r1 = __fsub_rn(w, bf2f(hi));        // exact
  u16 mid = f2bf(r1);
  if (sel == 1) return mid;
  float r2 = __fsub_rn(r1, bf2f(mid));      // exact
  return f2bf(r2);
}

__global__ __launch_bounds__(256) void prep_kernel(
    const float* __restrict__ W1, const float* __restrict__ W2,
    const float* __restrict__ Wo, u16* __restrict__ ws)
{
  int i = blockIdx.x * 256 + threadIdx.x;
  if (i < W1TOT) {                          // W1 [256][1280]
    int sel = i / 327680, rem = i - sel * 327680;
    int kc = rem >> 14, r = rem & 16383, j = r >> 6, kk = r & 63;
    float w = W1[j * 1280 + kc * 64 + kk];
    ws[i] = split3(w, sel);
  } else if (i < WOS_OFF) {                 // W2 [256][256]
    int i2 = i - W2S_OFF;
    int sel = i2 >> 16, rem = i2 & 65535;
    int kc = rem >> 14, j = (rem >> 6) & 255, kk = rem & 63;
    float w = W2[j * 256 + kc * 64 + kk];
    ws[i] = split3(w, sel);
  } else if (i < WS_TOTAL) {                // Wo [80][256] padded to 128 rows
    int i3 = i - WOS_OFF;
    int sel = i3 >> 15, rem = i3 & 32767;
    int kc = rem >> 13, j = (rem >> 6) & 127, kk = rem & 63;
    float w = (j < NO) ? Wo[j * 256 + kc * 64 + kk] : 0.f;
    ws[i] = split3(w, sel);
  }
}

// cooperative expansion of one 64-bit K-chunk of spike bits -> bf16 LDS tile
__device__ __forceinline__ void expandA(
    u16 (*buf)[AP], const u16* bits, int bpitch, int kreal, int tid)
{
  #pragma unroll
  for (int it = 0; it < 3; ++it) {          // ceil(2560/1024)
    int idx = tid + it * NTHR;
    if (idx < NROW * 32) {
      int row = idx >> 5, pr = idx & 31;
      int t = row >> 4, r = row & 15;
      int kg = (kreal << 6) + (pr << 1);
      u16 w = bits[(t * RR + r) * bpitch + (kg >> 4)];
      int bp = kg & 15;
      u32 val = ((w >> bp) & 1) ? 0x3F80u : 0u;
      if ((w >> (bp + 1)) & 1) val |= 0x3F800000u;
      *(u32*)(&buf[row][pr << 1]) = val;
    }
  }
}

// Merged-split GEMM: per K-chunk, A expanded once (double-buffered LDS),
// B fragments loaded per-wave directly from global (L2-resident ws).
// sel=0 (hi) -> accA ; sel=1,2 (mid,lo) -> accB. One 16-col tile per wave.
__device__ __forceinline__ void gemm_merged(
    u16 (*ldsA)[NROW][AP],
    const u16* __restrict__ wsbase, int selstride, int nkreal, int nrowB,
    const u16* bits, int bpitch,
    int tid, int lane, int ct0, bool active,
    f32x4 accA[TT], f32x4 accB[TT])
{
  const int m16 = lane & 15, q = lane >> 4;
  const int rowoff = (ct0 * 16 + m16) * 64 + q * 8;   // u16 units within chunk

  expandA(ldsA[0], bits, bpitch, 0, tid);
  __syncthreads();

  for (int kr = 0; kr < nkreal; ++kr) {
    const int par = kr & 1;
    if (active) {
      const u16* cbase = wsbase + kr * (nrowB * 64);
      #pragma unroll
      for (int ks = 0; ks < 2; ++ks) {
        bf16x8 afr[TT];
        #pragma unroll
        for (int t = 0; t < TT; ++t)
          afr[t] = *(const bf16x8*)(&ldsA[par][t * 16 + m16][ks * 32 + q * 8]);
        #pragma unroll
        for (int sel = 0; sel < 3; ++sel) {
          const bf16x8 bfr = *(const bf16x8*)(cbase + sel * selstride + ks * 32 + rowoff);
          f32x4* acc = sel ? accB : accA;
          #pragma unroll
          for (int t = 0; t < TT; ++t)
            acc[t] = __builtin_amdgcn_mfma_f32_16x16x32_bf16(afr[t], bfr, acc[t], 0, 0, 0);
        }
      }
    }
    if (kr + 1 < nkreal) expandA(ldsA[par ^ 1], bits, bpitch, kr + 1, tid);
    __syncthreads();
  }
}

// LIF recurrence over t on accumulated u(t); emit spike bits via ballot
__device__ __forceinline__ void recur_spikes(
    f32x4 acc[TT], const float* __restrict__ bias,
    int lane, int ct0, u16* sbits /* [TT][RR][16] words */)
{
  const int q = lane >> 4, m16 = lane & 15;
  int j = ct0 * 16 + m16;
  float bj = bias[j];
  #pragma unroll
  for (int rg = 0; rg < 4; ++rg) {
    float c = 0.f, v = 0.f, sprev = 0.f;
    #pragma unroll
    for (int t = 0; t < TT; ++t) {
      float u = acc[t][rg];
      c = __fadd_rn(__fadd_rn(__fmul_rn(c, 0.5f), u), bj);       // (c*0.5 + u) + b
      float vd = __fmul_rn(v, 0.75f);
      v = __fadd_rn((sprev > 0.5f) ? 0.f : vd, c);               // v*0.75*(1-s) + c
      bool sp = v > 0.5f;
      u64 mask = __ballot(sp);
      if (m16 == 0) {
        int row = q * 4 + rg;
        sbits[(t * RR + row) * 16 + ct0] = (u16)(mask >> (q * 16));
      }
      sprev = sp ? 1.f : 0.f;
    }
  }
}

__global__ __launch_bounds__(NTHR) void snn_main(
    const float* __restrict__ obs, const float* __restrict__ enc_mean, const float* __restrict__ enc_std,
    const float* __restrict__ b1, const float* __restrict__ b2, const float* __restrict__ bo,
    const float* __restrict__ dec_w, const float* __restrict__ dec_b, const float* __restrict__ log_std,
    const u16* __restrict__ wsW, float* __restrict__ out, int Btot)
{
  __shared__ __align__(16) char smem[2 * NROW * AP * 2 + 12800];
  u16 (*ldsA)[NROW][AP] = (u16(*)[NROW][AP])smem;             // 2*80*72*2 = 23040
  u16* encb = (u16*)(smem + 2 * NROW * AP * 2);               // [5][16][80] u16 = 12800 B
  u16* s1b  = encb;                                           // [5][16][16] (alias: encb dead after layer1)
  u16* s2b  = encb + TT * RR * 16;                            // [5][16][16]
  float* soacc = (float*)(encb + 2 * TT * RR * 16);           // [16][80] f32 (tail of enc region)

  const int tid  = threadIdx.x;
  const int lane = tid & 63;
  const int wv   = tid >> 6;          // 0..15
  const int r0   = blockIdx.x * RR;

  // ---------- population encoder -> spike bits for all T ----------
  for (int slot = tid; slot < RR * 20; slot += NTHR) {
    int r = slot / 20, c = slot - (slot / 20) * 20;
    u64 bits[TT] = {0, 0, 0, 0, 0};
    const float* obsrow = obs + (r0 + r) * NOBS;
    for (int e = 0; e < 64; ++e) {
      int k = c * 64 + e;
      int f = k / 10;
      float x  = obsrow[f];
      float m  = enc_mean[k];
      float sd = enc_std[k];
      float d  = __fsub_rn(x, m);
      float arg = __fdiv_rn(__fmul_rn(-0.5f, __fmul_rn(d, d)), __fmul_rn(sd, sd));
      float a = (float)exp((double)arg);   // correctly-rounded f32 exp of f32 arg
      float v = 0.f;
      #pragma unroll
      for (int t = 0; t < TT; ++t) {
        v = __fadd_rn(v, a);
        if (v > 0.999f) { bits[t] |= (1ull << e); v = __fsub_rn(v, 0.999f); }
      }
    }
    #pragma unroll
    for (int t = 0; t < TT; ++t) {
      u16* dst = encb + (t * RR + r) * 80 + c * 4;
      u64 bt = bits[t];
      dst[0] = (u16)bt; dst[1] = (u16)(bt >> 16);
      dst[2] = (u16)(bt >> 32); dst[3] = (u16)(bt >> 48);
    }
  }
  __syncthreads();

  f32x4 accA[TT], accB[TT];
  const f32x4 zero4 = {0.f, 0.f, 0.f, 0.f};
#define ZERO_ACC() { _Pragma("unroll") for (int t = 0; t < TT; ++t) { accA[t] = zero4; accB[t] = zero4; } }
#define COMBINE()  { _Pragma("unroll") for (int t = 0; t < TT; ++t) accA[t] += accB[t]; }

  // ---------- layer 1: [80 x 1280] @ [1280 x 256] (3-way split fused) ----------
  ZERO_ACC();
  gemm_merged(ldsA, wsW, 327680, 20, 256, encb, 80, tid, lane, wv, true, accA, accB);
  COMBINE();
  recur_spikes(accA, b1, lane, wv, s1b);
  __syncthreads();

  // ---------- layer 2: [80 x 256] @ [256 x 256] ----------
  ZERO_ACC();
  gemm_merged(ldsA, wsW + W2S_OFF, 65536, 4, 256, s1b, 16, tid, lane, wv, true, accA, accB);
  COMBINE();
  recur_spikes(accA, b2, lane, wv, s2b);
  __syncthreads();

  // ---------- layer 3: [80 x 256] @ [256 x 80(pad128)] — waves 0..7 compute ----------
  ZERO_ACC();
  gemm_merged(ldsA, wsW + WOS_OFF, 32768, 4, 128, s2b, 16, tid, lane, wv, (wv < 8), accA, accB);
  COMBINE();
  if (wv < 8) {
    const int q = lane >> 4, m16 = lane & 15;
    int j = wv * 16 + m16;
    bool valid = j < NO;
    float bj = valid ? bo[j] : 0.f;
    #pragma unroll
    for (int rg = 0; rg < 4; ++rg) {
      float c = 0.f, v = 0.f, sprev = 0.f;
      int cnt = 0;
      #pragma unroll
      for (int t = 0; t < TT; ++t) {
        float u = accA[t][rg];
        c = __fadd_rn(__fadd_rn(__fmul_rn(c, 0.5f), u), bj);
        float vd = __fmul_rn(v, 0.75f);
        v = __fadd_rn((sprev > 0.5f) ? 0.f : vd, c);
        bool sp = v > 0.5f;
        cnt += sp ? 1 : 0;
        sprev = sp ? 1.f : 0.f;
      }
      if (valid) soacc[(q * 4 + rg) * NO + j] = __fdiv_rn((float)cnt, 5.0f);
    }
  }
  __syncthreads();

  // ---------- decoder: grouped dot + ELU ----------
  if (tid < RR * 8) {
    int r = tid >> 3, a = tid & 7;
    float s = 0.f;
    const float* so = soacc + r * NO + a * 10;
    #pragma unroll
    for (int p = 0; p < 10; ++p)
      s = __fadd_rn(s, __fmul_rn(so[p], dec_w[a * 10 + p]));
    s = __fadd_rn(s, dec_b[a]);
    float mu = (s > 0.f) ? s : expm1f(s);
    out[(r0 + r) * 8 + a] = mu;
  }
  if (blockIdx.x == 0 && tid < 8) {
    out[Btot * 8 + tid] = expf(log_std[tid]);
  }
}

extern "C" void kernel_launch(void* const* d_in, const int* in_sizes, int n_in,
                              void* d_out, int out_size, void* d_ws, size_t ws_size,
                              hipStream_t stream) {
  const float* obs      = (const float*)d_in[0];
  const float* enc_mean = (const float*)d_in[1];
  const float* enc_std  = (const float*)d_in[2];
  const float* W1       = (const float*)d_in[3];
  const float* b1       = (const float*)d_in[4];
  const float* W2       = (const float*)d_in[5];
  const float* b2       = (const float*)d_in[6];
  const float* Wo       = (const float*)d_in[7];
  const float* bo       = (const float*)d_in[8];
  const float* dec_w    = (const float*)d_in[9];
  const float* dec_b    = (const float*)d_in[10];
  const float* log_std  = (const float*)d_in[11];
  u16*   ws  = (u16*)d_ws;
  float* out = (float*)d_out;
  int B = in_sizes[0] / NOBS;   // 8192

  hipLaunchKernelGGL(prep_kernel, dim3(WS_TOTAL / 256), dim3(256), 0, stream,
                     W1, W2, Wo, ws);
  hipLaunchKernelGGL(snn_main, dim3(B / RR), dim3(NTHR), 0, stream,
                     obs, enc_mean, enc_std, b1, b2, bo, dec_w, dec_b, log_std, ws, out, B);
}